// Round 1
// baseline (552.510 us; speedup 1.0000x reference)
//
#include <hip/hip_runtime.h>

#define NNODES 50000
#define INC 128
#define HC 64      // HEADS*OUT_C
#define NHEADS 4

// ---------------------------------------------------------------------------
// K1: xw = x @ W  [N,64], plus per-node logits a_src[n,h], a_dst[n,h]
// block = 256 (4 waves), each wave computes one node's 64 outputs.
// W staged in LDS (32 KB), x rows staged in LDS, grid-stride over node chunks.
// ---------------------------------------------------------------------------
__global__ __launch_bounds__(256) void proj_kernel(
    const float* __restrict__ x, const float* __restrict__ W,
    const float* __restrict__ att_s, const float* __restrict__ att_d,
    float* __restrict__ xw, float* __restrict__ a_src, float* __restrict__ a_dst)
{
    __shared__ float Wl[INC * HC];   // 32 KB
    __shared__ float xl[4][INC];     // 2 KB
    const int t = threadIdx.x;
    for (int i = t; i < INC * HC; i += 256) Wl[i] = W[i];

    const int w = t >> 6;   // wave 0..3
    const int o = t & 63;   // out channel
    const int h = o >> 4;
    const float as = att_s[o];
    const float ad = att_d[o];

    for (int n0 = blockIdx.x * 4; n0 < NNODES; n0 += gridDim.x * 4) {
        __syncthreads();
        // stage 4 rows of x (512 floats) cooperatively
        for (int i = t; i < 4 * INC; i += 256)
            xl[i >> 7][i & 127] = x[(size_t)(n0 + (i >> 7)) * INC + (i & 127)];
        __syncthreads();

        const int n = n0 + w;
        float acc = 0.f;
        #pragma unroll 8
        for (int i = 0; i < INC; ++i)
            acc = fmaf(xl[w][i], Wl[i * HC + o], acc);

        xw[(size_t)n * HC + o] = acc;

        float ps = acc * as;
        float pd = acc * ad;
        #pragma unroll
        for (int off = 8; off >= 1; off >>= 1) {
            ps += __shfl_xor(ps, off, 64);
            pd += __shfl_xor(pd, off, 64);
        }
        if ((o & 15) == 0) {
            a_src[n * NHEADS + h] = ps;
            a_dst[n * NHEADS + h] = pd;
        }
    }
}

// ---------------------------------------------------------------------------
// K2: single fused edge pass. One wave per edge; lane o = h*16+c.
//   ex[h]   = exp(leaky_relu(a_src[src,h] + a_dst[dst,h]))   (no amax needed:
//             softmax is shift-invariant and alpha is O(1) here)
//   agg[dst,o]   += ex * xw[src,o]        (deferred division by denom)
//   denom[dst,h] += ex
// ---------------------------------------------------------------------------
__global__ __launch_bounds__(256) void edge_kernel(
    const int* __restrict__ ei, const float* __restrict__ xw,
    const float* __restrict__ a_src, const float* __restrict__ a_dst,
    float* __restrict__ agg, float* __restrict__ denom, int E)
{
    const int o = threadIdx.x & 63;
    const int h = o >> 4;
    const int wid = blockIdx.x * 4 + (threadIdx.x >> 6);
    const int nw = gridDim.x * 4;

    for (int e = wid; e < E; e += nw) {
        const int s = ei[e];
        const int d = ei[E + e];
        const float av = a_src[s * NHEADS + h] + a_dst[d * NHEADS + h];
        const float alpha = av > 0.f ? av : 0.2f * av;
        const float ex = __expf(alpha);
        const float xv = xw[(size_t)s * HC + o];
        atomicAdd(&agg[(size_t)d * HC + o], ex * xv);
        if ((o & 15) == 0) atomicAdd(&denom[d * NHEADS + h], ex);
    }
}

// ---------------------------------------------------------------------------
// K3: per-node finalize: v = agg/denom + bias; u = elu(v); y = u . W_out + b
// One wave per node.
// ---------------------------------------------------------------------------
__global__ __launch_bounds__(256) void out_kernel(
    const float* __restrict__ agg, const float* __restrict__ denom,
    const float* __restrict__ bias, const float* __restrict__ Wo,
    const float* __restrict__ bo, float* __restrict__ y)
{
    const int t = threadIdx.x;
    const int o = t & 63;
    const int n = blockIdx.x * 4 + (t >> 6);

    const float den = denom[n * NHEADS + (o >> 4)] + 1e-16f;
    const float v = agg[(size_t)n * HC + o] / den + bias[o];
    const float u = v > 0.f ? v : (__expf(v) - 1.f);   // elu, alpha=1
    float p = u * Wo[o];
    #pragma unroll
    for (int off = 32; off >= 1; off >>= 1) p += __shfl_xor(p, off, 64);
    if (o == 0) y[n] = p + bo[0];
}

extern "C" void kernel_launch(void* const* d_in, const int* in_sizes, int n_in,
                              void* d_out, int out_size, void* d_ws, size_t ws_size,
                              hipStream_t stream) {
    const float* x     = (const float*)d_in[0];
    const int*   ei    = (const int*)d_in[1];   // [2,E] int32 (JAX x64 disabled)
    const float* W     = (const float*)d_in[2];
    const float* att_s = (const float*)d_in[3];
    const float* att_d = (const float*)d_in[4];
    const float* bias  = (const float*)d_in[5];
    const float* Wo    = (const float*)d_in[6];
    const float* bo    = (const float*)d_in[7];
    float*       y     = (float*)d_out;

    const int E = in_sizes[1] / 2;

    // workspace layout (floats): [xw N*64 | a_src N*4 | a_dst N*4 | denom N*4 | agg N*64]
    float* ws    = (float*)d_ws;
    float* xw    = ws;
    float* a_src = xw    + (size_t)NNODES * HC;
    float* a_dst = a_src + (size_t)NNODES * NHEADS;
    float* denom = a_dst + (size_t)NNODES * NHEADS;
    float* agg   = denom + (size_t)NNODES * NHEADS;

    // zero denom+agg (contiguous region, 68 floats per node)
    hipMemsetAsync(denom, 0, (size_t)NNODES * (NHEADS + HC) * sizeof(float), stream);

    proj_kernel<<<1024, 256, 0, stream>>>(x, W, att_s, att_d, xw, a_src, a_dst);
    edge_kernel<<<4096, 256, 0, stream>>>(ei, xw, a_src, a_dst, agg, denom, E);
    out_kernel<<<NNODES / 4, 256, 0, stream>>>(agg, denom, bias, Wo, bo, y);
}

// Round 2
// 540.060 us; speedup vs baseline: 1.0231x; 1.0231x over previous
//
#include <hip/hip_runtime.h>

#define NNODES 50000
#define INC 128
#define HC 64      // HEADS*OUT_C
#define NHEADS 4

// ---------------------------------------------------------------------------
// K1: xw = x @ W  [N,64], plus per-node logits a_src[n,h], a_dst[n,h].
// 256 threads = 4 waves; each wave computes TWO nodes (reuses each W element
// for 2 FMAs -> halves LDS read per FLOP). Grid-stride so W is staged once
// per block for ~24 node-groups.
// ---------------------------------------------------------------------------
__global__ __launch_bounds__(256) void proj_kernel(
    const float* __restrict__ x, const float* __restrict__ W,
    const float* __restrict__ att_s, const float* __restrict__ att_d,
    float* __restrict__ xw, float* __restrict__ a_src, float* __restrict__ a_dst)
{
    __shared__ float Wl[INC * HC];   // 32 KB
    __shared__ float xl[8][INC];     // 4 KB
    const int t = threadIdx.x;
    for (int i = t; i < INC * HC; i += 256) Wl[i] = W[i];

    const int w = t >> 6;   // wave 0..3
    const int o = t & 63;   // out channel
    const int h = o >> 4;
    const float as = att_s[o];
    const float ad = att_d[o];

    for (int n0 = blockIdx.x * 8; n0 < NNODES; n0 += gridDim.x * 8) {
        __syncthreads();
        for (int i = t; i < 8 * INC; i += 256)
            xl[i >> 7][i & 127] = x[(size_t)(n0 + (i >> 7)) * INC + (i & 127)];
        __syncthreads();

        float acca = 0.f, accb = 0.f;
        #pragma unroll 4
        for (int i = 0; i < INC; ++i) {
            const float wv = Wl[i * HC + o];
            acca = fmaf(xl[w][i],     wv, acca);
            accb = fmaf(xl[w + 4][i], wv, accb);
        }

        const int na = n0 + w, nb = n0 + 4 + w;
        xw[(size_t)na * HC + o] = acca;
        xw[(size_t)nb * HC + o] = accb;

        float psa = acca * as, pda = acca * ad;
        float psb = accb * as, pdb = accb * ad;
        #pragma unroll
        for (int off = 8; off >= 1; off >>= 1) {
            psa += __shfl_xor(psa, off, 64);
            pda += __shfl_xor(pda, off, 64);
            psb += __shfl_xor(psb, off, 64);
            pdb += __shfl_xor(pdb, off, 64);
        }
        if ((o & 15) == 0) {
            a_src[na * NHEADS + h] = psa;
            a_dst[na * NHEADS + h] = pda;
            a_src[nb * NHEADS + h] = psb;
            a_dst[nb * NHEADS + h] = pdb;
        }
    }
}

// ---------------------------------------------------------------------------
// K2a: histogram of dst degrees (int atomics, 1.6M ops)
// ---------------------------------------------------------------------------
__global__ __launch_bounds__(256) void hist_kernel(
    const int* __restrict__ ei, int* __restrict__ count, int E)
{
    for (int i = blockIdx.x * 256 + threadIdx.x; i < E; i += gridDim.x * 256)
        atomicAdd(&count[ei[E + i]], 1);
}

// ---------------------------------------------------------------------------
// K2b: single-block exclusive scan of count -> rowptr (and cursor copy)
// ---------------------------------------------------------------------------
__global__ __launch_bounds__(1024) void scan_kernel(
    const int* __restrict__ count, int* __restrict__ rowptr, int* __restrict__ cursor)
{
    __shared__ int part[1024];
    const int t = threadIdx.x;
    const int CH = (NNODES + 1023) / 1024;   // 49
    const int base = t * CH;

    int s = 0;
    for (int k = 0; k < CH; ++k) {
        const int idx = base + k;
        if (idx < NNODES) s += count[idx];
    }
    part[t] = s;
    __syncthreads();
    // inclusive Hillis-Steele scan over the 1024 partials
    for (int off = 1; off < 1024; off <<= 1) {
        const int u = (t >= off) ? part[t - off] : 0;
        __syncthreads();
        part[t] += u;
        __syncthreads();
    }
    int run = part[t] - s;   // exclusive start for this thread's chunk
    for (int k = 0; k < CH; ++k) {
        const int idx = base + k;
        if (idx < NNODES) {
            rowptr[idx] = run;
            cursor[idx] = run;
            run += count[idx];
        }
    }
    if (t == 1023) rowptr[NNODES] = run;
}

// ---------------------------------------------------------------------------
// K2c: scatter edges into CSR order (1.6M int atomics + 4B writes)
// ---------------------------------------------------------------------------
__global__ __launch_bounds__(256) void scatter_kernel(
    const int* __restrict__ ei, int* __restrict__ cursor,
    int* __restrict__ sorted_src, int E)
{
    for (int i = blockIdx.x * 256 + threadIdx.x; i < E; i += gridDim.x * 256) {
        const int d = ei[E + i];
        const int pos = atomicAdd(&cursor[d], 1);
        sorted_src[pos] = ei[i];
    }
}

// ---------------------------------------------------------------------------
// K3: aggregate + finalize, one wave per dst node, zero atomics.
//   acc[o]  = sum_e ex_e * xw[src_e, o]    (registers)
//   den     = sum_e ex_e                    (per-lane, head-uniform)
//   y[n]    = elu(acc/den + bias) . W_out + b_out
// softmax max-subtraction dropped (shift-invariant; alpha is O(1) here).
// ---------------------------------------------------------------------------
__global__ __launch_bounds__(256) void agg_kernel(
    const int* __restrict__ rowptr, const int* __restrict__ sorted_src,
    const float* __restrict__ xw, const float* __restrict__ a_src,
    const float* __restrict__ a_dst, const float* __restrict__ bias,
    const float* __restrict__ Wo, const float* __restrict__ bo,
    float* __restrict__ y)
{
    const int lane = threadIdx.x & 63;
    const int h = lane >> 4;
    const int n = blockIdx.x * 4 + (threadIdx.x >> 6);

    const int beg = rowptr[n], end = rowptr[n + 1];
    const float ad = a_dst[n * NHEADS + h];

    float acc = 0.f, den = 0.f;
    int i = beg;
    // full 64-edge chunks: no bounds check, unrolled for load ILP
    for (; i + 64 <= end; i += 64) {
        const int sv = sorted_src[i + lane];
        #pragma unroll 8
        for (int j = 0; j < 64; ++j) {
            const int s = __shfl(sv, j);
            const float av = a_src[s * NHEADS + h] + ad;
            const float ex = __expf(av > 0.f ? av : 0.2f * av);
            den += ex;
            acc = fmaf(ex, xw[(size_t)s * HC + lane], acc);
        }
    }
    // tail
    if (i < end) {
        const int m = end - i;
        const int sv = sorted_src[i + (lane < m ? lane : 0)];
        #pragma unroll 4
        for (int j = 0; j < m; ++j) {
            const int s = __shfl(sv, j);
            const float av = a_src[s * NHEADS + h] + ad;
            const float ex = __expf(av > 0.f ? av : 0.2f * av);
            den += ex;
            acc = fmaf(ex, xw[(size_t)s * HC + lane], acc);
        }
    }

    const float v = acc / (den + 1e-16f) + bias[lane];
    const float u = v > 0.f ? v : (__expf(v) - 1.f);   // elu
    float p = u * Wo[lane];
    #pragma unroll
    for (int off = 32; off >= 1; off >>= 1) p += __shfl_xor(p, off, 64);
    if (lane == 0) y[n] = p + bo[0];
}

extern "C" void kernel_launch(void* const* d_in, const int* in_sizes, int n_in,
                              void* d_out, int out_size, void* d_ws, size_t ws_size,
                              hipStream_t stream) {
    const float* x     = (const float*)d_in[0];
    const int*   ei    = (const int*)d_in[1];   // [2,E] int32
    const float* W     = (const float*)d_in[2];
    const float* att_s = (const float*)d_in[3];
    const float* att_d = (const float*)d_in[4];
    const float* bias  = (const float*)d_in[5];
    const float* Wo    = (const float*)d_in[6];
    const float* bo    = (const float*)d_in[7];
    float*       y     = (float*)d_out;

    const int E = in_sizes[1] / 2;

    // workspace layout (4B units):
    // [xw N*64 | a_src N*4 | a_dst N*4 | count N | rowptr N+1 | cursor N | sorted_src E]
    float* ws    = (float*)d_ws;
    float* xw    = ws;
    float* a_src = xw    + (size_t)NNODES * HC;
    float* a_dst = a_src + (size_t)NNODES * NHEADS;
    int*   count = (int*)(a_dst + (size_t)NNODES * NHEADS);
    int*   rowptr = count + NNODES;
    int*   cursor = rowptr + NNODES + 1;
    int*   sorted_src = cursor + NNODES;

    hipMemsetAsync(count, 0, NNODES * sizeof(int), stream);

    proj_kernel<<<2048, 256, 0, stream>>>(x, W, att_s, att_d, xw, a_src, a_dst);
    hist_kernel<<<4096, 256, 0, stream>>>(ei, count, E);
    scan_kernel<<<1, 1024, 0, stream>>>(count, rowptr, cursor);
    scatter_kernel<<<4096, 256, 0, stream>>>(ei, cursor, sorted_src, E);
    agg_kernel<<<NNODES / 4, 256, 0, stream>>>(rowptr, sorted_src, xw, a_src,
                                               a_dst, bias, Wo, bo, y);
}